// Round 7
// baseline (1701.240 us; speedup 1.0000x reference)
//
#include <hip/hip_runtime.h>
#include <hip/hip_bf16.h>

#define N_NODES 100000
#define N_EDGES 3200000
#define N_GRAPHS 512
#define NBUK 391               // dst buckets of 256 nodes
#define CAP 10240              // fixed slot capacity per bucket (mean 8184, sigma~90)
#define FILL_CHUNK 16384
#define FILL_BLOCKS ((N_EDGES + FILL_CHUNK - 1) / FILL_CHUNK)   // 196
#define ACC_STRIDE 33          // padded LDS accumulator row (breaks bank alignment)

__device__ __forceinline__ float blo(unsigned v) { return __uint_as_float(v << 16); }
__device__ __forceinline__ float bhi(unsigned v) { return __uint_as_float(v & 0xffff0000u); }

// ---------- pass 1: bin edges into fixed bucket slots, rank-trick (1 LDS atomic/edge) ----
__global__ __launch_bounds__(1024) void k_binfill(const int* __restrict__ ei,
                                                  int* __restrict__ gcnt,
                                                  unsigned* __restrict__ packed) {
    __shared__ int h[NBUK];
    __shared__ int base[NBUK];
    int t = threadIdx.x;
    for (int i = t; i < NBUK; i += 1024) h[i] = 0;
    __syncthreads();
    int s0 = blockIdx.x * FILL_CHUNK;
    int ng = min(FILL_CHUNK, N_EDGES - s0) >> 2;   // 4-entry groups
    const int4* src4 = (const int4*)(ei + s0);
    const int4* dst4 = (const int4*)(ei + N_EDGES + s0);
    int4 sv[4], dv[4];
    int  rk[4][4];
#pragma unroll
    for (int g = 0; g < 4; g++) {
        int gi = t + g * 1024;
        if (gi < ng) {
            sv[g] = src4[gi];
            dv[g] = dst4[gi];
            rk[g][0] = atomicAdd(&h[dv[g].x >> 8], 1);
            rk[g][1] = atomicAdd(&h[dv[g].y >> 8], 1);
            rk[g][2] = atomicAdd(&h[dv[g].z >> 8], 1);
            rk[g][3] = atomicAdd(&h[dv[g].w >> 8], 1);
        }
    }
    __syncthreads();
    for (int i = t; i < NBUK; i += 1024) {
        int c = h[i];
        base[i] = c ? atomicAdd(&gcnt[i], c) : 0;
    }
    __syncthreads();
#pragma unroll
    for (int g = 0; g < 4; g++) {
        int gi = t + g * 1024;
        if (gi < ng) {
            int s[4] = {sv[g].x, sv[g].y, sv[g].z, sv[g].w};
            int d[4] = {dv[g].x, dv[g].y, dv[g].z, dv[g].w};
#pragma unroll
            for (int k = 0; k < 4; k++) {
                int bk = d[k] >> 8;
                int pos = bk * CAP + base[bk] + rk[g][k];
                packed[pos] = (unsigned)s[k] | (((unsigned)d[k] & 255u) << 17);
            }
        }
    }
}

// ---------- pass 2 (diagnostic-light): per-bucket degree -> dinv, graph counts ----------
// Histogram only: no scan, no scattered writes, no-return atomics.
__global__ __launch_bounds__(1024) void k_degb(const unsigned* __restrict__ packed,
                                               const int* __restrict__ gcnt,
                                               const int* __restrict__ batch,
                                               float* __restrict__ dinv,
                                               int* __restrict__ cnt) {
    __shared__ int deg[256];
    int t = threadIdx.x;
    int b = blockIdx.x;
    if (t < 256) deg[t] = 0;
    __syncthreads();
    int n = gcnt[b];
    const unsigned* pb = packed + (size_t)b * CAP;
#pragma unroll
    for (int g = 0; g < 3; g++) {
        int i0 = 4 * (t + g * 1024);
        if (i0 < n) {
            uint4 p = *(const uint4*)(pb + i0);   // slot region always allocated
            if (i0 + 0 < n) atomicAdd(&deg[p.x >> 17], 1);
            if (i0 + 1 < n) atomicAdd(&deg[p.y >> 17], 1);
            if (i0 + 2 < n) atomicAdd(&deg[p.z >> 17], 1);
            if (i0 + 3 < n) atomicAdd(&deg[p.w >> 17], 1);
        }
    }
    __syncthreads();
    if (t < 256) {
        int node = b * 256 + t;
        if (node < N_NODES) {
            dinv[node] = rsqrtf((float)deg[t] + 1.0f);
            atomicAdd(&cnt[batch[node]], 1);
        }
    }
}

// ---------- H1s = bf16( (x @ W1) * dinv[row] )  ([100000,128] @ [128,32]) ----------
__global__ void k_gemm1(const float* __restrict__ x, const float* __restrict__ W1,
                        const float* __restrict__ dinv, __hip_bfloat16* __restrict__ H1s) {
    __shared__ float Ws[128 * 32];
    __shared__ float xs[32 * 128];
    int t = threadIdx.x;
    const float4* W4 = (const float4*)W1;
    float4* Ws4 = (float4*)Ws;
#pragma unroll
    for (int i = 0; i < 4; i++) Ws4[t + 256 * i] = W4[t + 256 * i];
    int row0 = blockIdx.x * 32;
    const float4* x4 = (const float4*)(x + (size_t)row0 * 128);
    float4* xs4 = (float4*)xs;
#pragma unroll
    for (int i = 0; i < 4; i++) xs4[t + 256 * i] = x4[t + 256 * i];
    __syncthreads();
    int col = t & 31;
    int rb = (t >> 5) * 4;
    float a0 = 0.f, a1 = 0.f, a2 = 0.f, a3 = 0.f;
#pragma unroll 8
    for (int k = 0; k < 128; k++) {
        float w = Ws[k * 32 + col];
        a0 += xs[(rb + 0) * 128 + k] * w;
        a1 += xs[(rb + 1) * 128 + k] * w;
        a2 += xs[(rb + 2) * 128 + k] * w;
        a3 += xs[(rb + 3) * 128 + k] * w;
    }
    int r = row0 + rb;
    __hip_bfloat16* o = H1s + (size_t)r * 32 + col;
    o[0]  = __float2bfloat16(a0 * dinv[r + 0]);
    o[32] = __float2bfloat16(a1 * dinv[r + 1]);
    o[64] = __float2bfloat16(a2 * dinv[r + 2]);
    o[96] = __float2bfloat16(a3 * dinv[r + 3]);
}

// ---------- H2s = bf16( (h1 @ W2) * dinv[row] )  ([100000,32] @ [32,32]) ----------
__global__ void k_gemm2(const float* __restrict__ h1, const float* __restrict__ W2,
                        const float* __restrict__ dinv, __hip_bfloat16* __restrict__ H2s) {
    __shared__ float Ws[32 * 32];
    __shared__ float xs[32 * 32];
    int t = threadIdx.x;
    ((float4*)Ws)[t] = ((const float4*)W2)[t];
    int row0 = blockIdx.x * 32;
    ((float4*)xs)[t] = ((const float4*)(h1 + (size_t)row0 * 32))[t];
    __syncthreads();
    int col = t & 31;
    int rb = (t >> 5) * 4;
    float a0 = 0.f, a1 = 0.f, a2 = 0.f, a3 = 0.f;
#pragma unroll
    for (int k = 0; k < 32; k++) {
        float w = Ws[k * 32 + col];
        a0 += xs[(rb + 0) * 32 + k] * w;
        a1 += xs[(rb + 1) * 32 + k] * w;
        a2 += xs[(rb + 2) * 32 + k] * w;
        a3 += xs[(rb + 3) * 32 + k] * w;
    }
    int r = row0 + rb;
    __hip_bfloat16* o = H2s + (size_t)r * 32 + col;
    o[0]  = __float2bfloat16(a0 * dinv[r + 0]);
    o[32] = __float2bfloat16(a1 * dinv[r + 1]);
    o[64] = __float2bfloat16(a2 * dinv[r + 2]);
    o[96] = __float2bfloat16(a3 * dinv[r + 3]);
}

// ---------- bucket-gather layer 1: block = bucket, LDS accumulator ----------
// 16 lanes per edge; acc[dl][f] += Hs[src][f]; epilogue: relu((acc+Hs[node])*dinv + b)
__global__ __launch_bounds__(1024) void k_bgather1(const __hip_bfloat16* __restrict__ Hs,
                                                   const float* __restrict__ dinv,
                                                   const unsigned* __restrict__ packed,
                                                   const int* __restrict__ gcnt,
                                                   const float* __restrict__ bias,
                                                   float* __restrict__ hout) {
    __shared__ float acc[256 * ACC_STRIDE];
    int t = threadIdx.x;
    int b = blockIdx.x;
    for (int i = t; i < 256 * ACC_STRIDE; i += 1024) acc[i] = 0.f;
    __syncthreads();
    int n = gcnt[b];
    const unsigned* pb = packed + (size_t)b * CAP;
    const unsigned* H32 = (const unsigned*)Hs;
    int f2 = t & 15;
    int e = t >> 4;            // 0..63 — 64 edges per block-iteration
    for (; e + 192 < n; e += 256) {
        unsigned p0 = pb[e];
        unsigned p1 = pb[e + 64];
        unsigned p2 = pb[e + 128];
        unsigned p3 = pb[e + 192];
        unsigned v0 = H32[(size_t)(p0 & 0x1FFFFu) * 16 + f2];
        unsigned v1 = H32[(size_t)(p1 & 0x1FFFFu) * 16 + f2];
        unsigned v2 = H32[(size_t)(p2 & 0x1FFFFu) * 16 + f2];
        unsigned v3 = H32[(size_t)(p3 & 0x1FFFFu) * 16 + f2];
        int d0 = (int)(p0 >> 17) * ACC_STRIDE + f2 * 2;
        int d1 = (int)(p1 >> 17) * ACC_STRIDE + f2 * 2;
        int d2 = (int)(p2 >> 17) * ACC_STRIDE + f2 * 2;
        int d3 = (int)(p3 >> 17) * ACC_STRIDE + f2 * 2;
        atomicAdd(&acc[d0], blo(v0)); atomicAdd(&acc[d0 + 1], bhi(v0));
        atomicAdd(&acc[d1], blo(v1)); atomicAdd(&acc[d1 + 1], bhi(v1));
        atomicAdd(&acc[d2], blo(v2)); atomicAdd(&acc[d2 + 1], bhi(v2));
        atomicAdd(&acc[d3], blo(v3)); atomicAdd(&acc[d3 + 1], bhi(v3));
    }
    for (; e < n; e += 64) {
        unsigned p = pb[e];
        unsigned v = H32[(size_t)(p & 0x1FFFFu) * 16 + f2];
        int d = (int)(p >> 17) * ACC_STRIDE + f2 * 2;
        atomicAdd(&acc[d], blo(v)); atomicAdd(&acc[d + 1], bhi(v));
    }
    __syncthreads();
    int node_l = t >> 2, off = (t & 3) * 8;
    int node = b * 256 + node_l;
    if (node < N_NODES) {
        float di = dinv[node];
        const float* ar = acc + node_l * ACC_STRIDE + off;
        uint4 hv = *(const uint4*)(H32 + (size_t)node * 16 + (off >> 1));
        float hb[8] = {blo(hv.x), bhi(hv.x), blo(hv.y), bhi(hv.y),
                       blo(hv.z), bhi(hv.z), blo(hv.w), bhi(hv.w)};
        float res[8];
#pragma unroll
        for (int j = 0; j < 8; j++)
            res[j] = fmaxf((ar[j] + hb[j]) * di + bias[off + j], 0.f);
        *(float4*)(hout + (size_t)node * 32 + off)     = make_float4(res[0], res[1], res[2], res[3]);
        *(float4*)(hout + (size_t)node * 32 + off + 4) = make_float4(res[4], res[5], res[6], res[7]);
    }
}

// ---------- bucket-gather layer 2 fused with mean-pool numerator ----------
__global__ __launch_bounds__(1024) void k_bgather2(const __hip_bfloat16* __restrict__ Hs,
                                                   const float* __restrict__ dinv,
                                                   const unsigned* __restrict__ packed,
                                                   const int* __restrict__ gcnt,
                                                   const float* __restrict__ bias,
                                                   const int* __restrict__ batch,
                                                   float* __restrict__ pool) {
    __shared__ float acc[256 * ACC_STRIDE];
    int t = threadIdx.x;
    int b = blockIdx.x;
    for (int i = t; i < 256 * ACC_STRIDE; i += 1024) acc[i] = 0.f;
    __syncthreads();
    int n = gcnt[b];
    const unsigned* pb = packed + (size_t)b * CAP;
    const unsigned* H32 = (const unsigned*)Hs;
    int f2 = t & 15;
    int e = t >> 4;
    for (; e + 192 < n; e += 256) {
        unsigned p0 = pb[e];
        unsigned p1 = pb[e + 64];
        unsigned p2 = pb[e + 128];
        unsigned p3 = pb[e + 192];
        unsigned v0 = H32[(size_t)(p0 & 0x1FFFFu) * 16 + f2];
        unsigned v1 = H32[(size_t)(p1 & 0x1FFFFu) * 16 + f2];
        unsigned v2 = H32[(size_t)(p2 & 0x1FFFFu) * 16 + f2];
        unsigned v3 = H32[(size_t)(p3 & 0x1FFFFu) * 16 + f2];
        int d0 = (int)(p0 >> 17) * ACC_STRIDE + f2 * 2;
        int d1 = (int)(p1 >> 17) * ACC_STRIDE + f2 * 2;
        int d2 = (int)(p2 >> 17) * ACC_STRIDE + f2 * 2;
        int d3 = (int)(p3 >> 17) * ACC_STRIDE + f2 * 2;
        atomicAdd(&acc[d0], blo(v0)); atomicAdd(&acc[d0 + 1], bhi(v0));
        atomicAdd(&acc[d1], blo(v1)); atomicAdd(&acc[d1 + 1], bhi(v1));
        atomicAdd(&acc[d2], blo(v2)); atomicAdd(&acc[d2 + 1], bhi(v2));
        atomicAdd(&acc[d3], blo(v3)); atomicAdd(&acc[d3 + 1], bhi(v3));
    }
    for (; e < n; e += 64) {
        unsigned p = pb[e];
        unsigned v = H32[(size_t)(p & 0x1FFFFu) * 16 + f2];
        int d = (int)(p >> 17) * ACC_STRIDE + f2 * 2;
        atomicAdd(&acc[d], blo(v)); atomicAdd(&acc[d + 1], bhi(v));
    }
    __syncthreads();
    int node_l = t >> 2, off = (t & 3) * 8;
    int node = b * 256 + node_l;
    if (node < N_NODES) {
        float di = dinv[node];
        const float* ar = acc + node_l * ACC_STRIDE + off;
        uint4 hv = *(const uint4*)(H32 + (size_t)node * 16 + (off >> 1));
        float hb[8] = {blo(hv.x), bhi(hv.x), blo(hv.y), bhi(hv.y),
                       blo(hv.z), bhi(hv.z), blo(hv.w), bhi(hv.w)};
        int g = batch[node];
#pragma unroll
        for (int j = 0; j < 8; j++) {
            float v = fmaxf((ar[j] + hb[j]) * di + bias[off + j], 0.f);
            atomicAdd(&pool[(size_t)g * 32 + off + j], v);
        }
    }
}

// ---------- head ----------
__global__ void k_final(const float* __restrict__ pool, const int* __restrict__ cnt,
                        const float* __restrict__ Wl, const float* __restrict__ bl,
                        float* __restrict__ out) {
    int g = blockIdx.x * 256 + threadIdx.x;
    if (g >= N_GRAPHS) return;
    float inv = 1.0f / fmaxf((float)cnt[g], 1.0f);
    float a0 = bl[0], a1 = bl[1];
#pragma unroll
    for (int f = 0; f < 32; f++) {
        float p = pool[g * 32 + f] * inv;
        a0 += p * Wl[f * 2 + 0];
        a1 += p * Wl[f * 2 + 1];
    }
    out[g * 2 + 0] = a0;
    out[g * 2 + 1] = a1;
}

extern "C" void kernel_launch(void* const* d_in, const int* in_sizes, int n_in,
                              void* d_out, int out_size, void* d_ws, size_t ws_size,
                              hipStream_t stream) {
    const float* x    = (const float*)d_in[0];
    const int*   ei   = (const int*)d_in[1];
    const int*   batch= (const int*)d_in[2];
    const float* W1   = (const float*)d_in[3];
    const float* b1   = (const float*)d_in[4];
    const float* W2   = (const float*)d_in[5];
    const float* b2   = (const float*)d_in[6];
    const float* Wl   = (const float*)d_in[7];
    const float* bl   = (const float*)d_in[8];
    float* out = (float*)d_out;

    char* w = (char*)d_ws;
    size_t off = 0;
    auto take = [&](size_t bytes) -> char* {
        char* p = w + off;
        off = (off + bytes + 255) & ~(size_t)255;
        return p;
    };
    __hip_bfloat16* H1s    = (__hip_bfloat16*)take((size_t)N_NODES * 32 * 2);
    __hip_bfloat16* H2s    = (__hip_bfloat16*)take((size_t)N_NODES * 32 * 2);
    float*          h1     = (float*)take((size_t)N_NODES * 32 * 4);
    unsigned*       packed = (unsigned*)take((size_t)NBUK * CAP * 4);   // lives through bgather2
    float*    dinv   = (float*)take((size_t)N_NODES * 4);
    int*      gcnt   = (int*)  take((size_t)NBUK * 4);
    float*    pool   = (float*)take((size_t)N_GRAPHS * 32 * 4);
    int*      cnt    = (int*)  take((size_t)N_GRAPHS * 4);

    hipMemsetAsync(gcnt, 0, (size_t)NBUK * 4, stream);
    hipMemsetAsync(pool, 0, (size_t)N_GRAPHS * 32 * 4, stream);
    hipMemsetAsync(cnt, 0, (size_t)N_GRAPHS * 4, stream);

    k_binfill <<<FILL_BLOCKS, 1024, 0, stream>>>(ei, gcnt, packed);
    k_degb    <<<NBUK, 1024, 0, stream>>>(packed, gcnt, batch, dinv, cnt);
    k_gemm1   <<<N_NODES / 32, 256, 0, stream>>>(x, W1, dinv, H1s);
    k_bgather1<<<NBUK, 1024, 0, stream>>>(H1s, dinv, packed, gcnt, b1, h1);
    k_gemm2   <<<N_NODES / 32, 256, 0, stream>>>(h1, W2, dinv, H2s);
    k_bgather2<<<NBUK, 1024, 0, stream>>>(H2s, dinv, packed, gcnt, b2, batch, pool);
    k_final   <<<2, 256, 0, stream>>>(pool, cnt, Wl, bl, out);
}

// Round 8
// 539.120 us; speedup vs baseline: 3.1556x; 3.1556x over previous
//
#include <hip/hip_runtime.h>
#include <hip/hip_bf16.h>

#define N_NODES 100000
#define N_EDGES 3200000
#define N_GRAPHS 512
#define NBUK 391               // dst buckets of 256 nodes
#define CAP 10240              // fixed slot capacity per bucket (mean 8184, sigma~90)
#define FILL_CHUNK 16384
#define FILL_BLOCKS ((N_EDGES + FILL_CHUNK - 1) / FILL_CHUNK)   // 196

__device__ __forceinline__ float blo(unsigned v) { return __uint_as_float(v << 16); }
__device__ __forceinline__ float bhi(unsigned v) { return __uint_as_float(v & 0xffff0000u); }

// ---------- pass 1: bin edges into bucket slots + global degree/rank ----------
// packed = rank<<25 | dstlocal<<17 | src   (rank = old deg[dst], exact within-node rank)
__global__ __launch_bounds__(1024) void k_binfill(const int* __restrict__ ei,
                                                  int* __restrict__ gcnt,
                                                  int* __restrict__ deg,
                                                  unsigned* __restrict__ packed) {
    __shared__ int h[NBUK];
    __shared__ int base[NBUK];
    int t = threadIdx.x;
    for (int i = t; i < NBUK; i += 1024) h[i] = 0;
    __syncthreads();
    int s0 = blockIdx.x * FILL_CHUNK;
    int ng = min(FILL_CHUNK, N_EDGES - s0) >> 2;   // 4-entry groups
    const int4* src4 = (const int4*)(ei + s0);
    const int4* dst4 = (const int4*)(ei + N_EDGES + s0);
    int4 sv[4], dv[4];
    int  rk[4][4], gr[4][4];
#pragma unroll
    for (int g = 0; g < 4; g++) {
        int gi = t + g * 1024;
        if (gi < ng) {
            sv[g] = src4[gi];
            dv[g] = dst4[gi];
            rk[g][0] = atomicAdd(&h[dv[g].x >> 8], 1);
            rk[g][1] = atomicAdd(&h[dv[g].y >> 8], 1);
            rk[g][2] = atomicAdd(&h[dv[g].z >> 8], 1);
            rk[g][3] = atomicAdd(&h[dv[g].w >> 8], 1);
            gr[g][0] = atomicAdd(&deg[dv[g].x], 1);
            gr[g][1] = atomicAdd(&deg[dv[g].y], 1);
            gr[g][2] = atomicAdd(&deg[dv[g].z], 1);
            gr[g][3] = atomicAdd(&deg[dv[g].w], 1);
        }
    }
    __syncthreads();
    for (int i = t; i < NBUK; i += 1024) {
        int c = h[i];
        base[i] = c ? atomicAdd(&gcnt[i], c) : 0;
    }
    __syncthreads();
#pragma unroll
    for (int g = 0; g < 4; g++) {
        int gi = t + g * 1024;
        if (gi < ng) {
            int s[4] = {sv[g].x, sv[g].y, sv[g].z, sv[g].w};
            int d[4] = {dv[g].x, dv[g].y, dv[g].z, dv[g].w};
#pragma unroll
            for (int k = 0; k < 4; k++) {
                int bk = d[k] >> 8;
                int pos = bk * CAP + base[bk] + rk[g][k];
                packed[pos] = (unsigned)s[k] | (((unsigned)d[k] & 255u) << 17)
                            | ((unsigned)gr[g][k] << 25);
            }
        }
    }
}

// ---------- scans: deg -> rp (exclusive), dinv ----------
__global__ void k_scan1(const int* __restrict__ deg, int* __restrict__ rp,
                        int* __restrict__ bsums, float* __restrict__ dinv) {
    __shared__ int sd[256];
    int t = threadIdx.x;
    int base = blockIdx.x * 1024 + t * 4;
    int v[4];
#pragma unroll
    for (int j = 0; j < 4; j++) {
        v[j] = (base + j < N_NODES) ? deg[base + j] : 0;
        if (base + j < N_NODES) dinv[base + j] = rsqrtf((float)v[j] + 1.0f);
    }
    int s = v[0] + v[1] + v[2] + v[3];
    sd[t] = s; __syncthreads();
    for (int off = 1; off < 256; off <<= 1) {
        int x = (t >= off) ? sd[t - off] : 0;
        __syncthreads(); sd[t] += x; __syncthreads();
    }
    if (t == 255) bsums[blockIdx.x] = sd[255];
    int excl = sd[t] - s;
#pragma unroll
    for (int j = 0; j < 4; j++) {
        if (base + j < N_NODES) rp[base + j] = excl;
        excl += v[j];
    }
}

__global__ void k_scan2(int* __restrict__ bsums, int nb) {
    __shared__ int sd[128];
    int t = threadIdx.x;
    int v = (t < nb) ? bsums[t] : 0;
    sd[t] = v; __syncthreads();
    for (int off = 1; off < 128; off <<= 1) {
        int x = (t >= off) ? sd[t - off] : 0;
        __syncthreads(); sd[t] += x; __syncthreads();
    }
    if (t < nb) bsums[t] = sd[t] - v;
}

__global__ void k_scan3(int* __restrict__ rp, int* __restrict__ rpe,
                        const int* __restrict__ bsums, const int* __restrict__ deg,
                        const int* __restrict__ batch, int* __restrict__ cnt) {
    int i = blockIdx.x * 256 + threadIdx.x;
    if (i < N_NODES) {
        int v = rp[i] + bsums[i >> 10];
        rp[i] = v;
        rpe[i] = v + deg[i];
        atomicAdd(&cnt[batch[i]], 1);
    }
}

// ---------- csr fill: zero atomics, bucket-localized writes ----------
__global__ __launch_bounds__(1024) void k_csrlite(const unsigned* __restrict__ packed,
                                                  const int* __restrict__ gcnt,
                                                  const int* __restrict__ rp,
                                                  int* __restrict__ csr) {
    __shared__ int rp_l[256];
    int t = threadIdx.x;
    int b = blockIdx.x;
    if (t < 256) {
        int node = b * 256 + t;
        rp_l[t] = (node < N_NODES) ? rp[node] : 0;
    }
    __syncthreads();
    int n = gcnt[b];
    const unsigned* pb = packed + (size_t)b * CAP;
    for (int i = t; i < n; i += 1024) {
        unsigned p = pb[i];
        csr[rp_l[(p >> 17) & 255u] + (int)(p >> 25)] = (int)(p & 0x1FFFFu);
    }
}

// ---------- H1s = bf16( (x @ W1) * dinv[row] ) ----------
__global__ void k_gemm1(const float* __restrict__ x, const float* __restrict__ W1,
                        const float* __restrict__ dinv, __hip_bfloat16* __restrict__ H1s) {
    __shared__ float Ws[128 * 32];
    __shared__ float xs[32 * 128];
    int t = threadIdx.x;
    const float4* W4 = (const float4*)W1;
    float4* Ws4 = (float4*)Ws;
#pragma unroll
    for (int i = 0; i < 4; i++) Ws4[t + 256 * i] = W4[t + 256 * i];
    int row0 = blockIdx.x * 32;
    const float4* x4 = (const float4*)(x + (size_t)row0 * 128);
    float4* xs4 = (float4*)xs;
#pragma unroll
    for (int i = 0; i < 4; i++) xs4[t + 256 * i] = x4[t + 256 * i];
    __syncthreads();
    int col = t & 31;
    int rb = (t >> 5) * 4;
    float a0 = 0.f, a1 = 0.f, a2 = 0.f, a3 = 0.f;
#pragma unroll 8
    for (int k = 0; k < 128; k++) {
        float w = Ws[k * 32 + col];
        a0 += xs[(rb + 0) * 128 + k] * w;
        a1 += xs[(rb + 1) * 128 + k] * w;
        a2 += xs[(rb + 2) * 128 + k] * w;
        a3 += xs[(rb + 3) * 128 + k] * w;
    }
    int r = row0 + rb;
    __hip_bfloat16* o = H1s + (size_t)r * 32 + col;
    o[0]  = __float2bfloat16(a0 * dinv[r + 0]);
    o[32] = __float2bfloat16(a1 * dinv[r + 1]);
    o[64] = __float2bfloat16(a2 * dinv[r + 2]);
    o[96] = __float2bfloat16(a3 * dinv[r + 3]);
}

// ---------- layer-1 gather FUSED with layer-2 transform ----------
// Butterfly allreduce leaves full h1 row in all 64 lanes; then
// H2s[node] = bf16( (relu(h1) @ W2) * dinv[node] ) via 16 shuffles+FMAs/lane.
__global__ void k_gather1(const __hip_bfloat16* __restrict__ Hs, const float* __restrict__ dinv,
                          const int* __restrict__ rp, const int* __restrict__ rpe,
                          const int* __restrict__ csr,
                          const float* __restrict__ b1, const float* __restrict__ W2,
                          __hip_bfloat16* __restrict__ H2s) {
    int wid = (blockIdx.x * 256 + threadIdx.x) >> 6;
    if (wid >= N_NODES) return;
    const unsigned* H32 = (const unsigned*)Hs;   // row stride 16 uints
    int lane = threadIdx.x & 63;
    int f2 = lane & 15;
    int q = lane >> 4;
    int f = lane & 31;
    int half = lane >> 5;
    float w2r[16];
#pragma unroll
    for (int j = 0; j < 16; j++) w2r[j] = W2[(half * 16 + j) * 32 + f];
    int beg = rp[wid], end = rpe[wid];
    float ax = 0.f, ay = 0.f;
    int e = beg + q;
    for (; e + 12 < end; e += 16) {
        int s0 = csr[e];
        int s1 = csr[e + 4];
        int s2 = csr[e + 8];
        int s3 = csr[e + 12];
        unsigned v0 = H32[(size_t)s0 * 16 + f2];
        unsigned v1 = H32[(size_t)s1 * 16 + f2];
        unsigned v2 = H32[(size_t)s2 * 16 + f2];
        unsigned v3 = H32[(size_t)s3 * 16 + f2];
        ax += blo(v0) + blo(v1) + blo(v2) + blo(v3);
        ay += bhi(v0) + bhi(v1) + bhi(v2) + bhi(v3);
    }
    for (; e < end; e += 4) {
        unsigned v = H32[(size_t)csr[e] * 16 + f2];
        ax += blo(v); ay += bhi(v);
    }
    ax += __shfl_xor(ax, 16); ay += __shfl_xor(ay, 16);
    ax += __shfl_xor(ax, 32); ay += __shfl_xor(ay, 32);   // allreduce: all 64 lanes full
    float di = dinv[wid];
    unsigned vw = H32[(size_t)wid * 16 + f2];
    float2 bb = *(const float2*)(b1 + f2 * 2);
    float vx = fmaxf((ax + blo(vw)) * di + bb.x, 0.f);   // relu(h1)[2*f2]
    float vy = fmaxf((ay + bhi(vw)) * di + bb.y, 0.f);   // relu(h1)[2*f2+1]
    // h2[f] = sum_k h1[k]*W2[k,f]; this lane sums k in [half*16, half*16+16)
    float acc = 0.f;
#pragma unroll
    for (int j = 0; j < 16; j += 2) {
        int sl = half * 8 + (j >> 1);
        acc += __shfl(vx, sl) * w2r[j];
        acc += __shfl(vy, sl) * w2r[j + 1];
    }
    acc += __shfl_xor(acc, 32);            // combine k-halves
    if (half == 0)
        H2s[(size_t)wid * 32 + f] = __float2bfloat16(acc * di);
}

// ---------- layer-2 aggregation fused with mean-pool numerator ----------
__global__ void k_gather2(const __hip_bfloat16* __restrict__ Hs, const float* __restrict__ dinv,
                          const int* __restrict__ rp, const int* __restrict__ rpe,
                          const int* __restrict__ csr,
                          const float* __restrict__ bias, const int* __restrict__ batch,
                          float* __restrict__ pool) {
    int wid = (blockIdx.x * 256 + threadIdx.x) >> 6;
    if (wid >= N_NODES) return;
    const unsigned* H32 = (const unsigned*)Hs;
    int lane = threadIdx.x & 63;
    int f2 = lane & 15;
    int q = lane >> 4;
    int beg = rp[wid], end = rpe[wid];
    float ax = 0.f, ay = 0.f;
    int e = beg + q;
    for (; e + 12 < end; e += 16) {
        int s0 = csr[e];
        int s1 = csr[e + 4];
        int s2 = csr[e + 8];
        int s3 = csr[e + 12];
        unsigned v0 = H32[(size_t)s0 * 16 + f2];
        unsigned v1 = H32[(size_t)s1 * 16 + f2];
        unsigned v2 = H32[(size_t)s2 * 16 + f2];
        unsigned v3 = H32[(size_t)s3 * 16 + f2];
        ax += blo(v0) + blo(v1) + blo(v2) + blo(v3);
        ay += bhi(v0) + bhi(v1) + bhi(v2) + bhi(v3);
    }
    for (; e < end; e += 4) {
        unsigned v = H32[(size_t)csr[e] * 16 + f2];
        ax += blo(v); ay += bhi(v);
    }
    ax += __shfl_xor(ax, 16); ay += __shfl_xor(ay, 16);
    ax += __shfl_xor(ax, 32); ay += __shfl_xor(ay, 32);
    if (q == 0) {
        float di = dinv[wid];
        unsigned vw = H32[(size_t)wid * 16 + f2];
        float2 bb = *(const float2*)(bias + f2 * 2);
        float vx = fmaxf((ax + blo(vw)) * di + bb.x, 0.f);
        float vy = fmaxf((ay + bhi(vw)) * di + bb.y, 0.f);
        int g = batch[wid];
        atomicAdd(&pool[(size_t)g * 32 + f2 * 2 + 0], vx);
        atomicAdd(&pool[(size_t)g * 32 + f2 * 2 + 1], vy);
    }
}

// ---------- head ----------
__global__ void k_final(const float* __restrict__ pool, const int* __restrict__ cnt,
                        const float* __restrict__ Wl, const float* __restrict__ bl,
                        float* __restrict__ out) {
    int g = blockIdx.x * 256 + threadIdx.x;
    if (g >= N_GRAPHS) return;
    float inv = 1.0f / fmaxf((float)cnt[g], 1.0f);
    float a0 = bl[0], a1 = bl[1];
#pragma unroll
    for (int f = 0; f < 32; f++) {
        float p = pool[g * 32 + f] * inv;
        a0 += p * Wl[f * 2 + 0];
        a1 += p * Wl[f * 2 + 1];
    }
    out[g * 2 + 0] = a0;
    out[g * 2 + 1] = a1;
}

extern "C" void kernel_launch(void* const* d_in, const int* in_sizes, int n_in,
                              void* d_out, int out_size, void* d_ws, size_t ws_size,
                              hipStream_t stream) {
    const float* x    = (const float*)d_in[0];
    const int*   ei   = (const int*)d_in[1];
    const int*   batch= (const int*)d_in[2];
    const float* W1   = (const float*)d_in[3];
    const float* b1   = (const float*)d_in[4];
    const float* W2   = (const float*)d_in[5];
    const float* b2   = (const float*)d_in[6];
    const float* Wl   = (const float*)d_in[7];
    const float* bl   = (const float*)d_in[8];
    float* out = (float*)d_out;

    char* w = (char*)d_ws;
    size_t off = 0;
    auto take = [&](size_t bytes) -> char* {
        char* p = w + off;
        off = (off + bytes + 255) & ~(size_t)255;
        return p;
    };
    __hip_bfloat16* H1s    = (__hip_bfloat16*)take((size_t)N_NODES * 32 * 2);
    // packed (16 MB) and H2s (6.4 MB) alias: packed dies at k_csrlite,
    // H2s is born in k_gather1 (after csrlite).
    char*           shared = take((size_t)NBUK * CAP * 4);
    unsigned*       packed = (unsigned*)shared;
    __hip_bfloat16* H2s    = (__hip_bfloat16*)shared;
    int*      csr    = (int*)  take((size_t)N_EDGES * 4);
    int*      deg    = (int*)  take((size_t)N_NODES * 4);
    float*    dinv   = (float*)take((size_t)N_NODES * 4);
    int*      rp     = (int*)  take((size_t)N_NODES * 4);
    int*      rpe    = (int*)  take((size_t)N_NODES * 4);
    int*      gcnt   = (int*)  take((size_t)NBUK * 4);
    int*      bsum   = (int*)  take(4096);
    float*    pool   = (float*)take((size_t)N_GRAPHS * 32 * 4);
    int*      cnt    = (int*)  take((size_t)N_GRAPHS * 4);

    hipMemsetAsync(deg, 0, (size_t)N_NODES * 4, stream);
    hipMemsetAsync(gcnt, 0, (size_t)NBUK * 4, stream);
    hipMemsetAsync(pool, 0, (size_t)N_GRAPHS * 32 * 4, stream);
    hipMemsetAsync(cnt, 0, (size_t)N_GRAPHS * 4, stream);

    const int nscan = (N_NODES + 1023) / 1024;  // 98
    k_binfill<<<FILL_BLOCKS, 1024, 0, stream>>>(ei, gcnt, deg, packed);
    k_scan1  <<<nscan, 256, 0, stream>>>(deg, rp, bsum, dinv);
    k_scan2  <<<1, 128, 0, stream>>>(bsum, nscan);
    k_scan3  <<<NBUK, 256, 0, stream>>>(rp, rpe, bsum, deg, batch, cnt);
    k_csrlite<<<NBUK, 1024, 0, stream>>>(packed, gcnt, rp, csr);
    k_gemm1  <<<N_NODES / 32, 256, 0, stream>>>(x, W1, dinv, H1s);
    k_gather1<<<N_NODES / 4, 256, 0, stream>>>(H1s, dinv, rp, rpe, csr, b1, W2, H2s);
    k_gather2<<<N_NODES / 4, 256, 0, stream>>>(H2s, dinv, rp, rpe, csr, b2, batch, pool);
    k_final  <<<2, 256, 0, stream>>>(pool, cnt, Wl, bl, out);
}

// Round 9
// 412.968 us; speedup vs baseline: 4.1195x; 1.3055x over previous
//
#include <hip/hip_runtime.h>
#include <hip/hip_bf16.h>

#define N_NODES 100000
#define N_EDGES 3200000
#define N_GRAPHS 512
#define NBUK 782               // dst buckets of 128 nodes: (100000+127)/128
#define CAP 4608               // slot capacity per bucket (mean 4092, sigma~64)
#define FILL_CHUNK 16384
#define FILL_BLOCKS ((N_EDGES + FILL_CHUNK - 1) / FILL_CHUNK)   // 196

__device__ __forceinline__ float blo(unsigned v) { return __uint_as_float(v << 16); }
__device__ __forceinline__ float bhi(unsigned v) { return __uint_as_float(v & 0xffff0000u); }

// ---------- pass 1: bin edges into fixed bucket slots (bucket = dst>>7) ----------
// packed = dstlocal<<17 | src  (dl 7 bits, src 17 bits)
__global__ __launch_bounds__(1024) void k_binfill(const int* __restrict__ ei,
                                                  int* __restrict__ gcnt,
                                                  unsigned* __restrict__ packed) {
    __shared__ int h[NBUK];
    __shared__ int base[NBUK];
    int t = threadIdx.x;
    for (int i = t; i < NBUK; i += 1024) h[i] = 0;
    __syncthreads();
    int s0 = blockIdx.x * FILL_CHUNK;
    int ng = min(FILL_CHUNK, N_EDGES - s0) >> 2;   // 4-entry groups
    const int4* src4 = (const int4*)(ei + s0);
    const int4* dst4 = (const int4*)(ei + N_EDGES + s0);
    int4 sv[4], dv[4];
    int  rk[4][4];
#pragma unroll
    for (int g = 0; g < 4; g++) {
        int gi = t + g * 1024;
        if (gi < ng) {
            sv[g] = src4[gi];
            dv[g] = dst4[gi];
            rk[g][0] = atomicAdd(&h[dv[g].x >> 7], 1);
            rk[g][1] = atomicAdd(&h[dv[g].y >> 7], 1);
            rk[g][2] = atomicAdd(&h[dv[g].z >> 7], 1);
            rk[g][3] = atomicAdd(&h[dv[g].w >> 7], 1);
        }
    }
    __syncthreads();
    for (int i = t; i < NBUK; i += 1024) {
        int c = h[i];
        base[i] = c ? atomicAdd(&gcnt[i], c) : 0;
    }
    __syncthreads();
#pragma unroll
    for (int g = 0; g < 4; g++) {
        int gi = t + g * 1024;
        if (gi < ng) {
            int s[4] = {sv[g].x, sv[g].y, sv[g].z, sv[g].w};
            int d[4] = {dv[g].x, dv[g].y, dv[g].z, dv[g].w};
#pragma unroll
            for (int k = 0; k < 4; k++) {
                int bk = d[k] >> 7;
                int pos = bk * CAP + base[bk] + rk[g][k];
                packed[pos] = (unsigned)s[k] | (((unsigned)d[k] & 127u) << 17);
            }
        }
    }
}

// ---------- pass 2: per-bucket deg/scan -> rp/rpe/dinv/cnt + slotted CSR ----------
// 128-node buckets, 512 threads: 782 blocks, 4 resident blocks/CU.
__global__ __launch_bounds__(512) void k_csr(const unsigned* __restrict__ packed,
                                             const int* __restrict__ gcnt,
                                             const int* __restrict__ batch,
                                             int* __restrict__ rp, int* __restrict__ rpe,
                                             float* __restrict__ dinv,
                                             int* __restrict__ csr, int* __restrict__ cnt) {
    __shared__ int deg[128];
    __shared__ int sd[128];
    __shared__ int nb0[128];
    int t = threadIdx.x;
    int b = blockIdx.x;
    if (t < 128) deg[t] = 0;
    __syncthreads();
    int n = gcnt[b];
    const unsigned* pb = packed + (size_t)b * CAP;
    unsigned pv[3][4];
    int rk[3][4];
#pragma unroll
    for (int g = 0; g < 3; g++) {
        int i0 = 4 * (t + g * 512);
        if (i0 < n) {
            uint4 p = *(const uint4*)(pb + i0);   // slot always allocated; tail guarded below
            pv[g][0] = p.x; pv[g][1] = p.y; pv[g][2] = p.z; pv[g][3] = p.w;
#pragma unroll
            for (int k = 0; k < 4; k++)
                if (i0 + k < n) rk[g][k] = atomicAdd(&deg[pv[g][k] >> 17], 1);
        }
    }
    __syncthreads();
    int d = (t < 128) ? deg[t] : 0;
    if (t < 128) sd[t] = d;
    __syncthreads();
    for (int off = 1; off < 128; off <<= 1) {
        int x = (t >= off && t < 128) ? sd[t - off] : 0;
        __syncthreads();
        if (t < 128) sd[t] += x;
        __syncthreads();
    }
    if (t < 128) {
        int pos0 = b * CAP + sd[t] - d;
        nb0[t] = pos0;
        int node = b * 128 + t;
        if (node < N_NODES) {
            rp[node] = pos0;
            rpe[node] = pos0 + d;
            dinv[node] = rsqrtf((float)d + 1.0f);
            atomicAdd(&cnt[batch[node]], 1);
        }
    }
    __syncthreads();
#pragma unroll
    for (int g = 0; g < 3; g++) {
        int i0 = 4 * (t + g * 512);
        if (i0 < n) {
#pragma unroll
            for (int k = 0; k < 4; k++) {
                if (i0 + k < n) {
                    unsigned p = pv[g][k];
                    csr[nb0[p >> 17] + rk[g][k]] = (int)(p & 0x1FFFFu);
                }
            }
        }
    }
}

// ---------- H1s = bf16( (x @ W1) * dinv[row] ) ----------
__global__ void k_gemm1(const float* __restrict__ x, const float* __restrict__ W1,
                        const float* __restrict__ dinv, __hip_bfloat16* __restrict__ H1s) {
    __shared__ float Ws[128 * 32];
    __shared__ float xs[32 * 128];
    int t = threadIdx.x;
    const float4* W4 = (const float4*)W1;
    float4* Ws4 = (float4*)Ws;
#pragma unroll
    for (int i = 0; i < 4; i++) Ws4[t + 256 * i] = W4[t + 256 * i];
    int row0 = blockIdx.x * 32;
    const float4* x4 = (const float4*)(x + (size_t)row0 * 128);
    float4* xs4 = (float4*)xs;
#pragma unroll
    for (int i = 0; i < 4; i++) xs4[t + 256 * i] = x4[t + 256 * i];
    __syncthreads();
    int col = t & 31;
    int rb = (t >> 5) * 4;
    float a0 = 0.f, a1 = 0.f, a2 = 0.f, a3 = 0.f;
#pragma unroll 8
    for (int k = 0; k < 128; k++) {
        float w = Ws[k * 32 + col];
        a0 += xs[(rb + 0) * 128 + k] * w;
        a1 += xs[(rb + 1) * 128 + k] * w;
        a2 += xs[(rb + 2) * 128 + k] * w;
        a3 += xs[(rb + 3) * 128 + k] * w;
    }
    int r = row0 + rb;
    __hip_bfloat16* o = H1s + (size_t)r * 32 + col;
    o[0]  = __float2bfloat16(a0 * dinv[r + 0]);
    o[32] = __float2bfloat16(a1 * dinv[r + 1]);
    o[64] = __float2bfloat16(a2 * dinv[r + 2]);
    o[96] = __float2bfloat16(a3 * dinv[r + 3]);
}

// ---------- layer-1 gather FUSED with layer-2 transform ----------
__global__ void k_gather1(const __hip_bfloat16* __restrict__ Hs, const float* __restrict__ dinv,
                          const int* __restrict__ rp, const int* __restrict__ rpe,
                          const int* __restrict__ csr,
                          const float* __restrict__ b1, const float* __restrict__ W2,
                          __hip_bfloat16* __restrict__ H2s) {
    int wid = (blockIdx.x * 256 + threadIdx.x) >> 6;
    if (wid >= N_NODES) return;
    const unsigned* H32 = (const unsigned*)Hs;   // row stride 16 uints
    int lane = threadIdx.x & 63;
    int f2 = lane & 15;
    int q = lane >> 4;
    int f = lane & 31;
    int half = lane >> 5;
    float w2r[16];
#pragma unroll
    for (int j = 0; j < 16; j++) w2r[j] = W2[(half * 16 + j) * 32 + f];
    int beg = rp[wid], end = rpe[wid];
    float ax = 0.f, ay = 0.f;
    int e = beg + q;
    for (; e + 12 < end; e += 16) {
        int s0 = csr[e];
        int s1 = csr[e + 4];
        int s2 = csr[e + 8];
        int s3 = csr[e + 12];
        unsigned v0 = H32[(size_t)s0 * 16 + f2];
        unsigned v1 = H32[(size_t)s1 * 16 + f2];
        unsigned v2 = H32[(size_t)s2 * 16 + f2];
        unsigned v3 = H32[(size_t)s3 * 16 + f2];
        ax += blo(v0) + blo(v1) + blo(v2) + blo(v3);
        ay += bhi(v0) + bhi(v1) + bhi(v2) + bhi(v3);
    }
    for (; e < end; e += 4) {
        unsigned v = H32[(size_t)csr[e] * 16 + f2];
        ax += blo(v); ay += bhi(v);
    }
    ax += __shfl_xor(ax, 16); ay += __shfl_xor(ay, 16);
    ax += __shfl_xor(ax, 32); ay += __shfl_xor(ay, 32);   // allreduce
    float di = dinv[wid];
    unsigned vw = H32[(size_t)wid * 16 + f2];
    float2 bb = *(const float2*)(b1 + f2 * 2);
    float vx = fmaxf((ax + blo(vw)) * di + bb.x, 0.f);
    float vy = fmaxf((ay + bhi(vw)) * di + bb.y, 0.f);
    float acc = 0.f;
#pragma unroll
    for (int j = 0; j < 16; j += 2) {
        int sl = half * 8 + (j >> 1);
        acc += __shfl(vx, sl) * w2r[j];
        acc += __shfl(vy, sl) * w2r[j + 1];
    }
    acc += __shfl_xor(acc, 32);
    if (half == 0)
        H2s[(size_t)wid * 32 + f] = __float2bfloat16(acc * di);
}

// ---------- layer-2 aggregation fused with mean-pool numerator ----------
__global__ void k_gather2(const __hip_bfloat16* __restrict__ Hs, const float* __restrict__ dinv,
                          const int* __restrict__ rp, const int* __restrict__ rpe,
                          const int* __restrict__ csr,
                          const float* __restrict__ bias, const int* __restrict__ batch,
                          float* __restrict__ pool) {
    int wid = (blockIdx.x * 256 + threadIdx.x) >> 6;
    if (wid >= N_NODES) return;
    const unsigned* H32 = (const unsigned*)Hs;
    int lane = threadIdx.x & 63;
    int f2 = lane & 15;
    int q = lane >> 4;
    int beg = rp[wid], end = rpe[wid];
    float ax = 0.f, ay = 0.f;
    int e = beg + q;
    for (; e + 12 < end; e += 16) {
        int s0 = csr[e];
        int s1 = csr[e + 4];
        int s2 = csr[e + 8];
        int s3 = csr[e + 12];
        unsigned v0 = H32[(size_t)s0 * 16 + f2];
        unsigned v1 = H32[(size_t)s1 * 16 + f2];
        unsigned v2 = H32[(size_t)s2 * 16 + f2];
        unsigned v3 = H32[(size_t)s3 * 16 + f2];
        ax += blo(v0) + blo(v1) + blo(v2) + blo(v3);
        ay += bhi(v0) + bhi(v1) + bhi(v2) + bhi(v3);
    }
    for (; e < end; e += 4) {
        unsigned v = H32[(size_t)csr[e] * 16 + f2];
        ax += blo(v); ay += bhi(v);
    }
    ax += __shfl_xor(ax, 16); ay += __shfl_xor(ay, 16);
    ax += __shfl_xor(ax, 32); ay += __shfl_xor(ay, 32);
    if (q == 0) {
        float di = dinv[wid];
        unsigned vw = H32[(size_t)wid * 16 + f2];
        float2 bb = *(const float2*)(bias + f2 * 2);
        float vx = fmaxf((ax + blo(vw)) * di + bb.x, 0.f);
        float vy = fmaxf((ay + bhi(vw)) * di + bb.y, 0.f);
        int g = batch[wid];
        atomicAdd(&pool[(size_t)g * 32 + f2 * 2 + 0], vx);
        atomicAdd(&pool[(size_t)g * 32 + f2 * 2 + 1], vy);
    }
}

// ---------- head ----------
__global__ void k_final(const float* __restrict__ pool, const int* __restrict__ cnt,
                        const float* __restrict__ Wl, const float* __restrict__ bl,
                        float* __restrict__ out) {
    int g = blockIdx.x * 256 + threadIdx.x;
    if (g >= N_GRAPHS) return;
    float inv = 1.0f / fmaxf((float)cnt[g], 1.0f);
    float a0 = bl[0], a1 = bl[1];
#pragma unroll
    for (int f = 0; f < 32; f++) {
        float p = pool[g * 32 + f] * inv;
        a0 += p * Wl[f * 2 + 0];
        a1 += p * Wl[f * 2 + 1];
    }
    out[g * 2 + 0] = a0;
    out[g * 2 + 1] = a1;
}

extern "C" void kernel_launch(void* const* d_in, const int* in_sizes, int n_in,
                              void* d_out, int out_size, void* d_ws, size_t ws_size,
                              hipStream_t stream) {
    const float* x    = (const float*)d_in[0];
    const int*   ei   = (const int*)d_in[1];
    const int*   batch= (const int*)d_in[2];
    const float* W1   = (const float*)d_in[3];
    const float* b1   = (const float*)d_in[4];
    const float* W2   = (const float*)d_in[5];
    const float* b2   = (const float*)d_in[6];
    const float* Wl   = (const float*)d_in[7];
    const float* bl   = (const float*)d_in[8];
    float* out = (float*)d_out;

    char* w = (char*)d_ws;
    size_t off = 0;
    auto take = [&](size_t bytes) -> char* {
        char* p = w + off;
        off = (off + bytes + 255) & ~(size_t)255;
        return p;
    };
    __hip_bfloat16* H1s    = (__hip_bfloat16*)take((size_t)N_NODES * 32 * 2);
    // packed (NBUK*CAP*4 = 14.4 MB) and H2s (6.4 MB) alias: packed dies at
    // k_csr; H2s is born in k_gather1.
    char*           shared = take((size_t)NBUK * CAP * 4);
    unsigned*       packed = (unsigned*)shared;
    __hip_bfloat16* H2s    = (__hip_bfloat16*)shared;
    int*      csr    = (int*)  take((size_t)NBUK * CAP * 4);
    float*    dinv   = (float*)take((size_t)N_NODES * 4);
    int*      rp     = (int*)  take((size_t)N_NODES * 4);
    int*      rpe    = (int*)  take((size_t)N_NODES * 4);
    int*      gcnt   = (int*)  take((size_t)NBUK * 4);
    float*    pool   = (float*)take((size_t)N_GRAPHS * 32 * 4);
    int*      cnt    = (int*)  take((size_t)N_GRAPHS * 4);

    hipMemsetAsync(gcnt, 0, (size_t)NBUK * 4, stream);
    hipMemsetAsync(pool, 0, (size_t)N_GRAPHS * 32 * 4, stream);
    hipMemsetAsync(cnt, 0, (size_t)N_GRAPHS * 4, stream);

    k_binfill<<<FILL_BLOCKS, 1024, 0, stream>>>(ei, gcnt, packed);
    k_csr    <<<NBUK, 512, 0, stream>>>(packed, gcnt, batch, rp, rpe, dinv, csr, cnt);
    k_gemm1  <<<N_NODES / 32, 256, 0, stream>>>(x, W1, dinv, H1s);
    k_gather1<<<N_NODES / 4, 256, 0, stream>>>(H1s, dinv, rp, rpe, csr, b1, W2, H2s);
    k_gather2<<<N_NODES / 4, 256, 0, stream>>>(H2s, dinv, rp, rpe, csr, b2, batch, pool);
    k_final  <<<2, 256, 0, stream>>>(pool, cnt, Wl, bl, out);
}